// Round 2
// baseline (126.830 us; speedup 1.0000x reference)
//
#include <hip/hip_runtime.h>

#define FEAT_D 4096
#define MARGIN_F 0.5f
#define EPS_F 1e-6f

__global__ __launch_bounds__(256) void triplet_loss_kernel(
    const float* __restrict__ features,
    const float* __restrict__ label,
    const int* __restrict__ idx1,
    const int* __restrict__ idx2,
    float* __restrict__ out)
{
    const int row = blockIdx.x;
    const int tid = threadIdx.x;
    const int i1 = idx1[row];   // uniform per block -> scalar load
    const int i2 = idx2[row];

    const float4* a  = reinterpret_cast<const float4*>(features + (size_t)row * FEAT_D) + tid;
    const float4* t1 = reinterpret_cast<const float4*>(features + (size_t)i1  * FEAT_D) + tid;
    const float4* t2 = reinterpret_cast<const float4*>(features + (size_t)i2  * FEAT_D) + tid;

    // Stage ALL loads first: 12 independent global_load_dwordx4 in flight
    // per thread (one memory-latency exposure per block instead of ~6).
    // All indices compile-time constant -> stays in VGPRs (no scratch).
    float4 va[4], v1[4], v2[4];
#pragma unroll
    for (int k = 0; k < 4; ++k) va[k] = a[k * 256];
#pragma unroll
    for (int k = 0; k < 4; ++k) v1[k] = t1[k * 256];
#pragma unroll
    for (int k = 0; k < 4; ++k) v2[k] = t2[k * 256];

    float s1 = 0.f, s2 = 0.f;
#pragma unroll
    for (int k = 0; k < 4; ++k) {
        float d;
        d = va[k].x - v1[k].x + EPS_F; s1 += d * d;
        d = va[k].y - v1[k].y + EPS_F; s1 += d * d;
        d = va[k].z - v1[k].z + EPS_F; s1 += d * d;
        d = va[k].w - v1[k].w + EPS_F; s1 += d * d;
        d = va[k].x - v2[k].x + EPS_F; s2 += d * d;
        d = va[k].y - v2[k].y + EPS_F; s2 += d * d;
        d = va[k].z - v2[k].z + EPS_F; s2 += d * d;
        d = va[k].w - v2[k].w + EPS_F; s2 += d * d;
    }

    // wave64 shuffle reduce
#pragma unroll
    for (int off = 32; off > 0; off >>= 1) {
        s1 += __shfl_down(s1, off, 64);
        s2 += __shfl_down(s2, off, 64);
    }

    __shared__ float sh1[4], sh2[4];
    const int wave = tid >> 6;
    const int lane = tid & 63;
    if (lane == 0) { sh1[wave] = s1; sh2[wave] = s2; }
    __syncthreads();

    if (tid == 0) {
        const float S1 = sh1[0] + sh1[1] + sh1[2] + sh1[3];
        const float S2 = sh2[0] + sh2[1] + sh2[2] + sh2[3];
        const float lab = label[row];
        const float d1 = fabsf(lab - label[i1]);
        const float d2 = fabsf(lab - label[i2]);
        const bool swap = (d1 >= d2);
        const float sn = swap ? S2 : S1;
        const float sf = swap ? S1 : S2;
        const float loss = fmaxf(sqrtf(sn) - sqrtf(sf) + MARGIN_F, 0.f);
        atomicAdd(out, loss);
    }
}

extern "C" void kernel_launch(void* const* d_in, const int* in_sizes, int n_in,
                              void* d_out, int out_size, void* d_ws, size_t ws_size,
                              hipStream_t stream) {
    const float* features = (const float*)d_in[0];
    const float* label    = (const float*)d_in[1];
    const int*   idx1     = (const int*)d_in[2];
    const int*   idx2     = (const int*)d_in[3];
    float* out = (float*)d_out;

    const int B = in_sizes[1];  // label has B elements ([B,1])

    hipMemsetAsync(out, 0, sizeof(float), stream);
    triplet_loss_kernel<<<B, 256, 0, stream>>>(features, label, idx1, idx2, out);
}

// Round 3
// 67.398 us; speedup vs baseline: 1.8818x; 1.8818x over previous
//
#include <hip/hip_runtime.h>

#define FEAT_D 4096
#define MARGIN_F 0.5f
#define EPS_F 1e-6f

__global__ __launch_bounds__(256) void triplet_loss_kernel(
    const float* __restrict__ features,
    const float* __restrict__ label,
    const int* __restrict__ idx1,
    const int* __restrict__ idx2,
    float* __restrict__ partials)
{
    const int row = blockIdx.x;
    const int tid = threadIdx.x;
    const int i1 = idx1[row];   // uniform per block -> scalar load
    const int i2 = idx2[row];

    const float4* a  = reinterpret_cast<const float4*>(features + (size_t)row * FEAT_D) + tid;
    const float4* t1 = reinterpret_cast<const float4*>(features + (size_t)i1  * FEAT_D) + tid;
    const float4* t2 = reinterpret_cast<const float4*>(features + (size_t)i2  * FEAT_D) + tid;

    float s1 = 0.f, s2 = 0.f;
#pragma unroll
    for (int k = 0; k < 4; ++k) {
        const float4 va = a[k * 256];
        const float4 v1 = t1[k * 256];
        const float4 v2 = t2[k * 256];
        float d;
        d = va.x - v1.x + EPS_F; s1 += d * d;
        d = va.y - v1.y + EPS_F; s1 += d * d;
        d = va.z - v1.z + EPS_F; s1 += d * d;
        d = va.w - v1.w + EPS_F; s1 += d * d;
        d = va.x - v2.x + EPS_F; s2 += d * d;
        d = va.y - v2.y + EPS_F; s2 += d * d;
        d = va.z - v2.z + EPS_F; s2 += d * d;
        d = va.w - v2.w + EPS_F; s2 += d * d;
    }

    // wave64 shuffle reduce
#pragma unroll
    for (int off = 32; off > 0; off >>= 1) {
        s1 += __shfl_down(s1, off, 64);
        s2 += __shfl_down(s2, off, 64);
    }

    __shared__ float sh1[4], sh2[4];
    const int wave = tid >> 6;
    const int lane = tid & 63;
    if (lane == 0) { sh1[wave] = s1; sh2[wave] = s2; }
    __syncthreads();

    if (tid == 0) {
        const float S1 = sh1[0] + sh1[1] + sh1[2] + sh1[3];
        const float S2 = sh2[0] + sh2[1] + sh2[2] + sh2[3];
        const float lab = label[row];
        const float d1 = fabsf(lab - label[i1]);
        const float d2 = fabsf(lab - label[i2]);
        const bool swap = (d1 >= d2);
        const float sn = swap ? S2 : S1;
        const float sf = swap ? S1 : S2;
        const float loss = fmaxf(sqrtf(sn) - sqrtf(sf) + MARGIN_F, 0.f);
        partials[row] = loss;   // no atomic: per-block store to distinct address
    }
}

__global__ __launch_bounds__(256) void reduce_kernel(
    const float* __restrict__ partials, float* __restrict__ out, int n)
{
    const int tid = threadIdx.x;
    float s = 0.f;
    const float4* p4 = reinterpret_cast<const float4*>(partials);
    for (int i = tid; i < n / 4; i += 256) {
        const float4 v = p4[i];
        s += (v.x + v.y) + (v.z + v.w);
    }
#pragma unroll
    for (int off = 32; off > 0; off >>= 1)
        s += __shfl_down(s, off, 64);

    __shared__ float sh[4];
    const int wave = tid >> 6;
    const int lane = tid & 63;
    if (lane == 0) sh[wave] = s;
    __syncthreads();
    if (tid == 0) out[0] = sh[0] + sh[1] + sh[2] + sh[3];
}

extern "C" void kernel_launch(void* const* d_in, const int* in_sizes, int n_in,
                              void* d_out, int out_size, void* d_ws, size_t ws_size,
                              hipStream_t stream) {
    const float* features = (const float*)d_in[0];
    const float* label    = (const float*)d_in[1];
    const int*   idx1     = (const int*)d_in[2];
    const int*   idx2     = (const int*)d_in[3];
    float* out      = (float*)d_out;
    float* partials = (float*)d_ws;   // B floats = 32 KB scratch

    const int B = in_sizes[1];  // label has B elements ([B,1])

    triplet_loss_kernel<<<B, 256, 0, stream>>>(features, label, idx1, idx2, partials);
    reduce_kernel<<<1, 256, 0, stream>>>(partials, out, B);
}

// Round 4
// 67.278 us; speedup vs baseline: 1.8852x; 1.0018x over previous
//
#include <hip/hip_runtime.h>

#define FEAT_D 4096
#define MARGIN_F 0.5f
#define EPS_F 1e-6f

__global__ __launch_bounds__(256) void triplet_loss_kernel(
    const float* __restrict__ features,
    const float* __restrict__ label,
    const int* __restrict__ idx1,
    const int* __restrict__ idx2,
    float* __restrict__ partials)
{
    const int row = blockIdx.x;
    const int tid = threadIdx.x;
    const int i1 = idx1[row];   // uniform per block -> scalar load
    const int i2 = idx2[row];

    const float4* a  = reinterpret_cast<const float4*>(features + (size_t)row * FEAT_D) + tid;
    const float4* t1 = reinterpret_cast<const float4*>(features + (size_t)i1  * FEAT_D) + tid;
    const float4* t2 = reinterpret_cast<const float4*>(features + (size_t)i2  * FEAT_D) + tid;

    // Stage ALL 12 global_load_dwordx4 first, then PIN with sched_barrier(0)
    // so the scheduler cannot sink loads into the compute (round-1 attempt
    // without the barrier was rolled back to a 2-in-flight chain, VGPR=28).
    float4 va[4], v1[4], v2[4];
#pragma unroll
    for (int k = 0; k < 4; ++k) va[k] = a[k * 256];
#pragma unroll
    for (int k = 0; k < 4; ++k) v1[k] = t1[k * 256];
#pragma unroll
    for (int k = 0; k < 4; ++k) v2[k] = t2[k * 256];
    __builtin_amdgcn_sched_barrier(0);

    float s1 = 0.f, s2 = 0.f;
#pragma unroll
    for (int k = 0; k < 4; ++k) {
        float d;
        d = va[k].x - v1[k].x + EPS_F; s1 += d * d;
        d = va[k].y - v1[k].y + EPS_F; s1 += d * d;
        d = va[k].z - v1[k].z + EPS_F; s1 += d * d;
        d = va[k].w - v1[k].w + EPS_F; s1 += d * d;
        d = va[k].x - v2[k].x + EPS_F; s2 += d * d;
        d = va[k].y - v2[k].y + EPS_F; s2 += d * d;
        d = va[k].z - v2[k].z + EPS_F; s2 += d * d;
        d = va[k].w - v2[k].w + EPS_F; s2 += d * d;
    }

    // wave64 shuffle reduce
#pragma unroll
    for (int off = 32; off > 0; off >>= 1) {
        s1 += __shfl_down(s1, off, 64);
        s2 += __shfl_down(s2, off, 64);
    }

    __shared__ float sh1[4], sh2[4];
    const int wave = tid >> 6;
    const int lane = tid & 63;
    if (lane == 0) { sh1[wave] = s1; sh2[wave] = s2; }
    __syncthreads();

    if (tid == 0) {
        const float S1 = sh1[0] + sh1[1] + sh1[2] + sh1[3];
        const float S2 = sh2[0] + sh2[1] + sh2[2] + sh2[3];
        const float lab = label[row];
        const float d1 = fabsf(lab - label[i1]);
        const float d2 = fabsf(lab - label[i2]);
        const bool swap = (d1 >= d2);
        const float sn = swap ? S2 : S1;
        const float sf = swap ? S1 : S2;
        const float loss = fmaxf(sqrtf(sn) - sqrtf(sf) + MARGIN_F, 0.f);
        partials[row] = loss;   // no atomic: per-block store to distinct address
    }
}

__global__ __launch_bounds__(256) void reduce_kernel(
    const float* __restrict__ partials, float* __restrict__ out, int n)
{
    const int tid = threadIdx.x;
    float s = 0.f;
    const float4* p4 = reinterpret_cast<const float4*>(partials);
    for (int i = tid; i < n / 4; i += 256) {
        const float4 v = p4[i];
        s += (v.x + v.y) + (v.z + v.w);
    }
#pragma unroll
    for (int off = 32; off > 0; off >>= 1)
        s += __shfl_down(s, off, 64);

    __shared__ float sh[4];
    const int wave = tid >> 6;
    const int lane = tid & 63;
    if (lane == 0) sh[wave] = s;
    __syncthreads();
    if (tid == 0) out[0] = sh[0] + sh[1] + sh[2] + sh[3];
}

extern "C" void kernel_launch(void* const* d_in, const int* in_sizes, int n_in,
                              void* d_out, int out_size, void* d_ws, size_t ws_size,
                              hipStream_t stream) {
    const float* features = (const float*)d_in[0];
    const float* label    = (const float*)d_in[1];
    const int*   idx1     = (const int*)d_in[2];
    const int*   idx2     = (const int*)d_in[3];
    float* out      = (float*)d_out;
    float* partials = (float*)d_ws;   // B floats = 32 KB scratch

    const int B = in_sizes[1];  // label has B elements ([B,1])

    triplet_loss_kernel<<<B, 256, 0, stream>>>(features, label, idx1, idx2, partials);
    reduce_kernel<<<1, 256, 0, stream>>>(partials, out, B);
}

// Round 5
// 63.376 us; speedup vs baseline: 2.0012x; 1.0616x over previous
//
#include <hip/hip_runtime.h>

#define FEAT_D 4096
#define MARGIN_F 0.5f
#define EPS_F 1e-6f
#define ROWS_PER_BLK 4

// Per-row: 12 float4 loads (a, t1, t2), fp32 accum of both squared distances,
// wave shuffle-reduce, per-wave LDS slot. Double-buffered across rows so the
// VMEM pipe never drains at row boundaries; one __syncthreads per block.

__global__ __launch_bounds__(256) void triplet_loss_kernel(
    const float* __restrict__ features,
    const float* __restrict__ label,
    const int* __restrict__ idx1,
    const int* __restrict__ idx2,
    float* __restrict__ partials)
{
    const int tid = threadIdx.x;
    const int row0 = blockIdx.x * ROWS_PER_BLK;

    __shared__ float sh1[ROWS_PER_BLK][4], sh2[ROWS_PER_BLK][4];

    float4 bufA[12], bufB[12];

#define ISSUE(BUF, R)                                                          \
    {                                                                          \
        const int rr_ = (R);                                                   \
        const int j1_ = idx1[rr_], j2_ = idx2[rr_];                            \
        const float4* pa_ = reinterpret_cast<const float4*>(features + (size_t)rr_ * FEAT_D) + tid; \
        const float4* p1_ = reinterpret_cast<const float4*>(features + (size_t)j1_ * FEAT_D) + tid; \
        const float4* p2_ = reinterpret_cast<const float4*>(features + (size_t)j2_ * FEAT_D) + tid; \
        _Pragma("unroll")                                                      \
        for (int k = 0; k < 4; ++k) BUF[k]     = pa_[k * 256];                 \
        _Pragma("unroll")                                                      \
        for (int k = 0; k < 4; ++k) BUF[4 + k] = p1_[k * 256];                 \
        _Pragma("unroll")                                                      \
        for (int k = 0; k < 4; ++k) BUF[8 + k] = p2_[k * 256];                 \
    }                                                                          \
    __builtin_amdgcn_sched_barrier(0);

#define COMPUTE(BUF, SLOT)                                                     \
    {                                                                          \
        float s1_ = 0.f, s2_ = 0.f;                                            \
        _Pragma("unroll")                                                      \
        for (int k = 0; k < 4; ++k) {                                          \
            float d_;                                                          \
            d_ = BUF[k].x - BUF[4+k].x + EPS_F; s1_ += d_ * d_;                \
            d_ = BUF[k].y - BUF[4+k].y + EPS_F; s1_ += d_ * d_;                \
            d_ = BUF[k].z - BUF[4+k].z + EPS_F; s1_ += d_ * d_;                \
            d_ = BUF[k].w - BUF[4+k].w + EPS_F; s1_ += d_ * d_;                \
            d_ = BUF[k].x - BUF[8+k].x + EPS_F; s2_ += d_ * d_;                \
            d_ = BUF[k].y - BUF[8+k].y + EPS_F; s2_ += d_ * d_;                \
            d_ = BUF[k].z - BUF[8+k].z + EPS_F; s2_ += d_ * d_;                \
            d_ = BUF[k].w - BUF[8+k].w + EPS_F; s2_ += d_ * d_;                \
        }                                                                      \
        _Pragma("unroll")                                                      \
        for (int off = 32; off > 0; off >>= 1) {                               \
            s1_ += __shfl_down(s1_, off, 64);                                  \
            s2_ += __shfl_down(s2_, off, 64);                                  \
        }                                                                      \
        if ((tid & 63) == 0) { sh1[SLOT][tid >> 6] = s1_; sh2[SLOT][tid >> 6] = s2_; } \
    }

    ISSUE(bufA, row0)
    ISSUE(bufB, row0 + 1)
    COMPUTE(bufA, 0)
    ISSUE(bufA, row0 + 2)
    COMPUTE(bufB, 1)
    ISSUE(bufB, row0 + 3)
    COMPUTE(bufA, 2)
    COMPUTE(bufB, 3)

    __syncthreads();

    if (tid < ROWS_PER_BLK) {
        const int r = row0 + tid;
        const float S1 = sh1[tid][0] + sh1[tid][1] + sh1[tid][2] + sh1[tid][3];
        const float S2 = sh2[tid][0] + sh2[tid][1] + sh2[tid][2] + sh2[tid][3];
        const float lab = label[r];
        const float d1 = fabsf(lab - label[idx1[r]]);
        const float d2 = fabsf(lab - label[idx2[r]]);
        const bool swap = (d1 >= d2);
        const float sn = swap ? S2 : S1;
        const float sf = swap ? S1 : S2;
        partials[r] = fmaxf(sqrtf(sn) - sqrtf(sf) + MARGIN_F, 0.f);
    }
#undef ISSUE
#undef COMPUTE
}

__global__ __launch_bounds__(1024) void reduce_kernel(
    const float* __restrict__ partials, float* __restrict__ out, int n)
{
    const int tid = threadIdx.x;
    float s = 0.f;
    const float4* p4 = reinterpret_cast<const float4*>(partials);
    for (int i = tid; i < n / 4; i += 1024) {
        const float4 v = p4[i];
        s += (v.x + v.y) + (v.z + v.w);
    }
#pragma unroll
    for (int off = 32; off > 0; off >>= 1)
        s += __shfl_down(s, off, 64);

    __shared__ float sh[16];
    const int wave = tid >> 6;
    const int lane = tid & 63;
    if (lane == 0) sh[wave] = s;
    __syncthreads();
    if (tid == 0) {
        float t = 0.f;
#pragma unroll
        for (int w = 0; w < 16; ++w) t += sh[w];
        out[0] = t;
    }
}

extern "C" void kernel_launch(void* const* d_in, const int* in_sizes, int n_in,
                              void* d_out, int out_size, void* d_ws, size_t ws_size,
                              hipStream_t stream) {
    const float* features = (const float*)d_in[0];
    const float* label    = (const float*)d_in[1];
    const int*   idx1     = (const int*)d_in[2];
    const int*   idx2     = (const int*)d_in[3];
    float* out      = (float*)d_out;
    float* partials = (float*)d_ws;   // B floats = 32 KB scratch

    const int B = in_sizes[1];  // label has B elements ([B,1])

    triplet_loss_kernel<<<B / ROWS_PER_BLK, 256, 0, stream>>>(features, label, idx1, idx2, partials);
    reduce_kernel<<<1, 1024, 0, stream>>>(partials, out, B);
}